// Round 2
// baseline (222.200 us; speedup 1.0000x reference)
//
#include <hip/hip_runtime.h>

#define EPS 1e-7f

typedef float fx4 __attribute__((ext_vector_type(4)));

// Params per channel: pa = {n0, n1, n2, B00}, pb = {g*mag, g-1, 0, 0}
__global__ __launch_bounds__(256) void lorentz_params_kernel(
    const float* __restrict__ Bo, fx4* __restrict__ P, int C)
{
    int c = blockIdx.x * blockDim.x + threadIdx.x;
    if (c >= C) return;
    float b0 = Bo[c * 3 + 0];
    float b1 = Bo[c * 3 + 1];
    float b2 = Bo[c * 3 + 2];
    float mag = sqrtf(b0 * b0 + b1 * b1 + b2 * b2);
    mag = fminf(fmaxf(mag, EPS), 1.0f - EPS);
    float inv = 1.0f / mag;
    float n0 = b0 * inv, n1 = b1 * inv, n2 = b2 * inv;
    float g = 1.0f / sqrtf(1.0f - mag * mag);
    float nn = n0 * n0 + n1 * n1 + n2 * n2;   // exactly mirrors ref's nK2[0][0]
    float B00 = 1.0f + (g - 1.0f) * nn;
    fx4 pa = {n0, n1, n2, B00};
    fx4 pb = {g * mag, g - 1.0f, 0.0f, 0.0f};
    P[c * 2 + 0] = pa;
    P[c * 2 + 1] = pb;
}

// One thread per (b,c) 4-vector. idx = b*C + c, C = 1024 (power of 2).
__global__ __launch_bounds__(256) void lorentz_apply_kernel(
    const fx4* __restrict__ T, const fx4* __restrict__ P,
    fx4* __restrict__ out, int total)
{
    int idx = blockIdx.x * blockDim.x + threadIdx.x;
    if (idx >= total) return;
    int c = idx & 1023;

    fx4 x  = __builtin_nontemporal_load(&T[idx]);
    fx4 pa = P[c * 2 + 0];   // cached (32 KB table, L1/L2 resident)
    fx4 pb = P[c * 2 + 1];

    float d  = pa.x * x.y + pa.y * x.z + pa.z * x.w;   // n . v
    float o0 = pa.w * x.x - pb.x * d;                  // B00*x0 - gm*d
    float s  = pb.y * d - pb.x * x.x;                  // gm1*d - gm*x0
    fx4 o = {o0,
             x.y + pa.x * s,
             x.z + pa.y * s,
             x.w + pa.z * s};
    __builtin_nontemporal_store(o, &out[idx]);
}

extern "C" void kernel_launch(void* const* d_in, const int* in_sizes, int n_in,
                              void* d_out, int out_size, void* d_ws, size_t ws_size,
                              hipStream_t stream)
{
    const fx4* T  = (const fx4*)d_in[0];
    const float* Bo = (const float*)d_in[1];
    fx4* out = (fx4*)d_out;
    fx4* P   = (fx4*)d_ws;

    int C = in_sizes[1] / 3;                 // 1024 channels
    int total = out_size / 4;                // number of 4-vectors (8192*1024)

    lorentz_params_kernel<<<(C + 255) / 256, 256, 0, stream>>>(Bo, P, C);
    lorentz_apply_kernel<<<(total + 255) / 256, 256, 0, stream>>>(T, P, out, total);
}